// Round 2
// baseline (156.724 us; speedup 1.0000x reference)
//
#include <hip/hip_runtime.h>

#define IN_N   4096
#define OW     4084          // (4096 + 2*1 - 15) + 1
#define KS     15
#define XS     88            // LDS row stride in halfwords (176 B: 16B-mult, odd dword-group stride -> conflict-free reads)
#define WROWS  30            // 16 output rows + 14 halo rows staged per wave
#define NBX    64            // col tiles of 64
#define NBY    128           // 2 row-tiles (one per wave) per block -> 256 row tiles

typedef __attribute__((ext_vector_type(8))) short     v8s;   // raw 16B
typedef __attribute__((ext_vector_type(8))) _Float16  v8h;   // f16 A/B frag (4 VGPR)
typedef __attribute__((ext_vector_type(4))) float     v4f;   // C/D frag
typedef __attribute__((ext_vector_type(2))) float     v2f;
typedef __attribute__((ext_vector_type(4))) unsigned  v4u;

// ---- pre-kernel: build the 15 banded-B MFMA fragments once into d_ws ----
// B_ky[k][n] = w[ky, k-1-n] (band in k ∈ [1,31)); A k-window starts at EVEN
// global col X0-2 (aligned float2 staging).
// lane e holds B[k = (e>>4)*8 + j][n = e&15], j = 0..7  (16 B per lane)
__global__ void build_B(const float* __restrict__ w, unsigned short* __restrict__ Bg) {
    int ky = blockIdx.x;         // 15
    int e  = threadIdx.x;        // 64
    int n = e & 15, quad = e >> 4;
    unsigned short vals[8];
    #pragma unroll
    for (int j = 0; j < 8; ++j) {
        int d = quad * 8 + j - 1 - n;                 // shifted band
        _Float16 h = (_Float16)0.0f;
        if (d >= 0 && d < KS) h = (_Float16)w[ky * KS + d];   // RTNE f32->f16
        union { _Float16 hh; unsigned short u; } cv; cv.hh = h;
        vals[j] = cv.u;
    }
    *(v8s*)(&Bg[(ky * 64 + e) * 8]) = *(const v8s*)vals;
}

__device__ __forceinline__ unsigned pk(float a, float b) {
    return __builtin_bit_cast(unsigned, __builtin_amdgcn_cvt_pkrtz(a, b));
}

// 2 waves per block, each wave FULLY independent (own LDS slice, no barrier).
__global__ __launch_bounds__(128, 7) void conv2d_mfma4(
    const float* __restrict__ x, const unsigned short* __restrict__ Bg,
    const float* __restrict__ bias, float* __restrict__ out)
{
    __shared__ unsigned short xtile[2 * WROWS * XS] __attribute__((aligned(16)));

    const int tid  = threadIdx.x;
    const int lane = tid & 63;
    const int wv   = tid >> 6;                    // 0..1
    const int bx   = blockIdx.x;
    const int RT   = blockIdx.y * 2 + wv;         // row-tile 0..255
    const int X0   = bx * 64;
    const int R0   = RT * 16;                     // first output row of this wave

    unsigned short* slice = &xtile[wv * (WROWS * XS)];

    // wave-interior test: staged region rows R0-1..R0+28, cols X0-2..X0+77
    const bool interior = (bx >= 1) & (bx <= 62) & (RT >= 1) & (RT <= 254);

    // ---- stage 30x80 fp32 -> f16 into this wave's slice ----
    // lanes 0..59: r0 = lane/10 (0..5), cu = lane%10 (8-float col unit)
    // 5 sweeps stepping 6 rows cover rows 0..29.
    if (lane < 60) {
        const int r0 = lane / 10;
        const int cu = lane % 10;
        unsigned short* dst = slice + r0 * XS + cu * 8;
        if (interior) {
            const float* xr = x + (size_t)(R0 - 1 + r0) * IN_N + (X0 - 2 + cu * 8);
            #pragma unroll
            for (int i = 0; i < 5; ++i) {
                v2f f0 = *(const v2f*)(xr + 0);   // 8B-aligned dwordx2
                v2f f1 = *(const v2f*)(xr + 2);
                v2f f2 = *(const v2f*)(xr + 4);
                v2f f3 = *(const v2f*)(xr + 6);
                v4u p;
                p.x = pk(f0.x, f0.y);
                p.y = pk(f1.x, f1.y);
                p.z = pk(f2.x, f2.y);
                p.w = pk(f3.x, f3.y);
                *(v4u*)dst = p;                   // ds_write_b128, 16B-aligned
                xr  += 6 * (size_t)IN_N;
                dst += 6 * XS;
            }
        } else {
            const int gc0 = X0 - 2 + cu * 8;
            #pragma unroll
            for (int i = 0; i < 5; ++i) {
                const int r  = r0 + 6 * i;        // 0..29
                const int gr = R0 - 1 + r;
                float f[8];
                #pragma unroll
                for (int j = 0; j < 8; ++j) f[j] = 0.0f;
                if ((unsigned)gr < (unsigned)IN_N) {
                    const float* xr = x + (size_t)gr * IN_N;
                    #pragma unroll
                    for (int j = 0; j < 8; ++j)
                        if ((unsigned)(gc0 + j) < (unsigned)IN_N) f[j] = xr[gc0 + j];
                }
                v4u p;
                p.x = pk(f[0], f[1]);
                p.y = pk(f[2], f[3]);
                p.z = pk(f[4], f[5]);
                p.w = pk(f[6], f[7]);
                *(v4u*)(slice + r * XS + cu * 8) = p;
            }
        }
    }

    // No __syncthreads: slice is wave-private. Same-wave DS ops are in-order;
    // drain writes and fence the compiler so no ds_read hoists above.
    asm volatile("s_waitcnt lgkmcnt(0)" ::: "memory");
    __builtin_amdgcn_sched_barrier(0);

    // ---- MFMA main loop (register-double-buffered over ky) ----
    const int m    = lane & 15;
    const int quad = lane >> 4;

    v4f acc[4];
    #pragma unroll
    for (int t = 0; t < 4; ++t) acc[t] = (v4f){0.f, 0.f, 0.f, 0.f};

    const v8h* Bgv = (const v8h*)Bg;
    const unsigned short* arow = slice + m * XS + quad * 8;

    v8h bcur = Bgv[lane];                          // ky = 0 (L2-resident)
    v8h a0 = *(const v8h*)(arow + 0);
    v8h a1 = *(const v8h*)(arow + 16);
    v8h a2 = *(const v8h*)(arow + 32);
    v8h a3 = *(const v8h*)(arow + 48);

    #pragma unroll
    for (int ky = 0; ky < KS; ++ky) {
        const unsigned short* nrow = arow + XS;
        v8h bn = bcur, n0 = a0, n1 = a1, n2 = a2, n3 = a3;
        if (ky < KS - 1) {
            bn = Bgv[(ky + 1) * 64 + lane];
            n0 = *(const v8h*)(nrow + 0);
            n1 = *(const v8h*)(nrow + 16);
            n2 = *(const v8h*)(nrow + 32);
            n3 = *(const v8h*)(nrow + 48);
        }
        acc[0] = __builtin_amdgcn_mfma_f32_16x16x32_f16(a0, bcur, acc[0], 0, 0, 0);
        acc[1] = __builtin_amdgcn_mfma_f32_16x16x32_f16(a1, bcur, acc[1], 0, 0, 0);
        acc[2] = __builtin_amdgcn_mfma_f32_16x16x32_f16(a2, bcur, acc[2], 0, 0, 0);
        acc[3] = __builtin_amdgcn_mfma_f32_16x16x32_f16(a3, bcur, acc[3], 0, 0, 0);
        a0 = n0; a1 = n1; a2 = n2; a3 = n3; bcur = bn;
        arow = nrow;
    }

    // ---- epilogue: D[m,n] -> out; row = quad*4 + r, col = m (+16t) ----
    const float bv = bias[0];
    const int orow0 = R0 + quad * 4;
    const int ocol0 = X0 + m;
    if ((bx < NBX - 1) & (RT < 255)) {
        float* o0 = &out[(size_t)orow0 * OW + ocol0];
        #pragma unroll
        for (int t = 0; t < 4; ++t) {
            #pragma unroll
            for (int r = 0; r < 4; ++r)
                o0[(size_t)r * OW + t * 16] = acc[t][r] + bv;
        }
    } else {
        #pragma unroll
        for (int t = 0; t < 4; ++t) {
            int oc = ocol0 + t * 16;
            if (oc < OW) {
                #pragma unroll
                for (int r = 0; r < 4; ++r) {
                    int orow = orow0 + r;
                    if (orow < OW)
                        out[(size_t)orow * OW + oc] = acc[t][r] + bv;
                }
            }
        }
    }
}

extern "C" void kernel_launch(void* const* d_in, const int* in_sizes, int n_in,
                              void* d_out, int out_size, void* d_ws, size_t ws_size,
                              hipStream_t stream) {
    const float* x    = (const float*)d_in[0];
    const float* w    = (const float*)d_in[1];
    const float* bias = (const float*)d_in[2];
    float* out        = (float*)d_out;
    unsigned short* Bg = (unsigned short*)d_ws;     // 15 KiB of scratch

    build_B<<<dim3(KS), dim3(64), 0, stream>>>(w, Bg);
    dim3 grid(NBX, NBY);
    conv2d_mfma4<<<grid, dim3(128), 0, stream>>>(x, Bg, bias, out);
}